// Round 1
// baseline (222.781 us; speedup 1.0000x reference)
//
#include <hip/hip_runtime.h>

typedef __attribute__((ext_vector_type(8))) __bf16 bf16x8;
typedef __attribute__((ext_vector_type(4))) float f32x4;
typedef __attribute__((ext_vector_type(8))) unsigned short u16x8;

#define MFMA16(a, b, c) __builtin_amdgcn_mfma_f32_16x16x32_bf16((a), (b), (c), 0, 0, 0)

__device__ __forceinline__ unsigned short f2bf(float f) {
    union { float f; unsigned int u; } v;
    v.f = f;
    unsigned int u = v.u;
    unsigned int r = (u + 0x7fffu + ((u >> 16) & 1u)) >> 16;
    return (unsigned short)r;
}

// ---------------------------------------------------------------- convert f32 -> bf16
__global__ void convert_f32_bf16(const float* __restrict__ src, unsigned short* __restrict__ dst, int n4) {
    int i = blockIdx.x * blockDim.x + threadIdx.x;
    if (i < n4) {
        float4 v = reinterpret_cast<const float4*>(src)[i];
        ushort4 o;
        o.x = f2bf(v.x); o.y = f2bf(v.y); o.z = f2bf(v.z); o.w = f2bf(v.w);
        reinterpret_cast<ushort4*>(dst)[i] = o;
    }
}

// ---------------------------------------------------------------- WkE / WvF fold (tiny)
// wcat rows [1024,2048): WkE[h*64+kk][c] = sum_d Wk[h,d,c]*E[h,d,kk]
// wcat rows [2048,3072): WvF[h*64+kk][c] = sum_d Wv[h,d,c]*F[h,d,kk]
__global__ void build_wkev(const float* __restrict__ Wk, const float* __restrict__ Wv,
                           const float* __restrict__ E, const float* __restrict__ F,
                           unsigned short* __restrict__ wcat) {
    int idx = blockIdx.x * 256 + threadIdx.x;          // 2M threads
    int c   = idx & 1023;
    int n2  = (idx >> 10) & 1023;
    int sel = idx >> 20;                                // 0 -> WkE, 1 -> WvF
    int h = n2 >> 6, kk = n2 & 63;
    const float* W  = sel ? Wv : Wk;
    const float* Ef = sel ? F : E;
    float acc = 0.f;
#pragma unroll 8
    for (int d = 0; d < 64; ++d)
        acc += W[(size_t)((h * 64 + d)) * 1024 + c] * Ef[(h * 64 + d) * 64 + kk];
    wcat[(size_t)(1024 + (sel << 10) + n2) * 1024 + c] = f2bf(acc);
}

// ---------------------------------------------------------------- bf16 GEMM, B^T layout
// C[m][n] = sum_k A[m][k] * Bt[n][k]
// MODE 0: scatter epilogue -> q[bh][t][d], kp[bh][t][d], vpT[bh][kk][t]
// MODE 1: out[m][n] = acc + bp[n]  (fp32)
template <int MODE>
__global__ __launch_bounds__(256) void gemm_bt(
    const unsigned short* __restrict__ A, const unsigned short* __restrict__ Bt, int K,
    unsigned short* __restrict__ qo, unsigned short* __restrict__ kpo, unsigned short* __restrict__ vpto,
    float* __restrict__ out, const float* __restrict__ bp) {
    __shared__ __align__(16) unsigned short As[128 * 32];
    __shared__ __align__(16) unsigned short Bs[128 * 32];
    const int tid = threadIdx.x;
    const int lane = tid & 63, wv = tid >> 6;
    const int g = lane >> 4, ln = lane & 15;
    const int wm = wv >> 1, wn = wv & 1;
    const int m0 = blockIdx.x * 128, n0 = blockIdx.y * 128;

    f32x4 acc[4][4];
#pragma unroll
    for (int i = 0; i < 4; ++i)
#pragma unroll
        for (int j = 0; j < 4; ++j) acc[i][j] = (f32x4){0.f, 0.f, 0.f, 0.f};

    const int c0 = tid, c1 = 256 + tid;
    const int row0 = c0 >> 2, k80 = c0 & 3;
    const int row1 = c1 >> 2, k81 = c1 & 3;

    const int nk = K >> 5;
    for (int kt = 0; kt < nk; ++kt) {
        const int kb = kt * 32;
        u16x8 ra0 = *reinterpret_cast<const u16x8*>(A + (size_t)(m0 + row0) * K + kb + k80 * 8);
        u16x8 ra1 = *reinterpret_cast<const u16x8*>(A + (size_t)(m0 + row1) * K + kb + k81 * 8);
        u16x8 rb0 = *reinterpret_cast<const u16x8*>(Bt + (size_t)(n0 + row0) * K + kb + k80 * 8);
        u16x8 rb1 = *reinterpret_cast<const u16x8*>(Bt + (size_t)(n0 + row1) * K + kb + k81 * 8);
        __syncthreads();
        *reinterpret_cast<u16x8*>(As + c0 * 8) = ra0;
        *reinterpret_cast<u16x8*>(As + c1 * 8) = ra1;
        *reinterpret_cast<u16x8*>(Bs + c0 * 8) = rb0;
        *reinterpret_cast<u16x8*>(Bs + c1 * 8) = rb1;
        __syncthreads();
        bf16x8 af[4], bfr[4];
#pragma unroll
        for (int i = 0; i < 4; ++i)
            af[i] = __builtin_bit_cast(bf16x8, *reinterpret_cast<const u16x8*>(As + (wm * 64 + i * 16 + ln) * 32 + g * 8));
#pragma unroll
        for (int j = 0; j < 4; ++j)
            bfr[j] = __builtin_bit_cast(bf16x8, *reinterpret_cast<const u16x8*>(Bs + (wn * 64 + j * 16 + ln) * 32 + g * 8));
#pragma unroll
        for (int i = 0; i < 4; ++i)
#pragma unroll
            for (int j = 0; j < 4; ++j)
                acc[i][j] = MFMA16(af[i], bfr[j], acc[i][j]);
    }

#pragma unroll
    for (int i = 0; i < 4; ++i) {
        const int mbase = m0 + wm * 64 + i * 16 + 4 * g;
#pragma unroll
        for (int j = 0; j < 4; ++j) {
            const int ncol = n0 + wn * 64 + j * 16 + ln;
#pragma unroll
            for (int r = 0; r < 4; ++r) {
                const int m = mbase + r;
                if (MODE == 0) {
                    const int b = m >> 11, t = m & 2047;
                    const int sec = ncol >> 10, nn = ncol & 1023;
                    const int h = nn >> 6, e = nn & 63;
                    const int bh = b * 16 + h;
                    unsigned short val = f2bf(acc[i][j][r]);
                    if (sec == 0)      qo[(size_t)(bh * 2048 + t) * 64 + e] = val;
                    else if (sec == 1) kpo[(size_t)(bh * 2048 + t) * 64 + e] = val;
                    else               vpto[(size_t)(bh * 64 + e) * 2048 + t] = val;
                } else {
                    out[(size_t)m * 1024 + ncol] = acc[i][j][r] + bp[ncol];
                }
            }
        }
    }
}

// ---------------------------------------------------------------- causal flash attention
// q,kp: [bh][t][64] bf16 ; vpT: [bh][64][2048] bf16 ; o: [b][t][h*64+kk] bf16
__global__ __launch_bounds__(256) void attn_kernel(
    const unsigned short* __restrict__ qg, const unsigned short* __restrict__ kpg,
    const unsigned short* __restrict__ vptg, unsigned short* __restrict__ og) {
    const int qt = blockIdx.x, bh = blockIdx.y;
    const int tid = threadIdx.x;
    const int lane = tid & 63, wv = tid >> 6;
    const int g = lane >> 4, ln = lane & 15;

    __shared__ __align__(16) unsigned short kps[64 * 64];
    __shared__ __align__(16) unsigned short vps[64 * 64];
    __shared__ __align__(16) unsigned short pls[4][16][72];   // per-wave P, padded rows (144B)

    const int qrow = qt * 64 + wv * 16 + ln;
    const unsigned short* qp = qg + (size_t)(bh * 2048 + qrow) * 64;
    const bf16x8 qa0 = __builtin_bit_cast(bf16x8, *reinterpret_cast<const u16x8*>(qp + g * 8));
    const bf16x8 qa1 = __builtin_bit_cast(bf16x8, *reinterpret_cast<const u16x8*>(qp + 32 + g * 8));

    f32x4 o[4];
#pragma unroll
    for (int nt = 0; nt < 4; ++nt) o[nt] = (f32x4){0.f, 0.f, 0.f, 0.f};
    float mrow[4] = {-1e30f, -1e30f, -1e30f, -1e30f};
    float lrow[4] = {0.f, 0.f, 0.f, 0.f};
    const float scale = 0.125f;   // 1/sqrt(64)

    for (int st = 0; st <= qt; ++st) {
        const int s0 = st * 64;
        __syncthreads();
#pragma unroll
        for (int rep = 0; rep < 2; ++rep) {
            const int c = rep * 256 + tid;
            const int row = c >> 3, k16 = c & 7;
            const int sw = k16 ^ (row & 7);   // XOR bank swizzle
            u16x8 kv = *reinterpret_cast<const u16x8*>(kpg + (size_t)(bh * 2048 + s0 + row) * 64 + k16 * 8);
            *reinterpret_cast<u16x8*>(kps + row * 64 + sw * 8) = kv;
            u16x8 vvv = *reinterpret_cast<const u16x8*>(vptg + (size_t)(bh * 64 + row) * 2048 + s0 + k16 * 8);
            *reinterpret_cast<u16x8*>(vps + row * 64 + sw * 8) = vvv;
        }
        __syncthreads();

        // S = Q * KP^T   (D rows = q 4g+r, cols = s j*16+ln)
        f32x4 sf[4];
#pragma unroll
        for (int j = 0; j < 4; ++j) {
            f32x4 a = (f32x4){0.f, 0.f, 0.f, 0.f};
            const int srow = j * 16 + ln;
#pragma unroll
            for (int ks = 0; ks < 2; ++ks) {
                const int chunk = (ks * 4 + g) ^ (srow & 7);
                bf16x8 bk = __builtin_bit_cast(bf16x8, *reinterpret_cast<const u16x8*>(kps + srow * 64 + chunk * 8));
                a = MFMA16(ks ? qa1 : qa0, bk, a);
            }
            sf[j] = a;
        }
        // scale + causal mask (diagonal tile only)
#pragma unroll
        for (int j = 0; j < 4; ++j) {
#pragma unroll
            for (int r = 0; r < 4; ++r) {
                float v = sf[j][r] * scale;
                if (st == qt) {
                    const int sg = s0 + j * 16 + ln;
                    const int qgl = qt * 64 + wv * 16 + 4 * g + r;
                    if (sg > qgl) v = -1e30f;
                }
                sf[j][r] = v;
            }
        }
        // online softmax
        float mp[4];
#pragma unroll
        for (int r = 0; r < 4; ++r) {
            float v = fmaxf(fmaxf(sf[0][r], sf[1][r]), fmaxf(sf[2][r], sf[3][r]));
            v = fmaxf(v, __shfl_xor(v, 1));
            v = fmaxf(v, __shfl_xor(v, 2));
            v = fmaxf(v, __shfl_xor(v, 4));
            v = fmaxf(v, __shfl_xor(v, 8));
            mp[r] = v;
        }
        float alpha[4];
#pragma unroll
        for (int r = 0; r < 4; ++r) {
            const float mn = fmaxf(mrow[r], mp[r]);
            alpha[r] = __expf(mrow[r] - mn);
            mrow[r] = mn;
        }
        float psum[4] = {0.f, 0.f, 0.f, 0.f};
#pragma unroll
        for (int j = 0; j < 4; ++j) {
#pragma unroll
            for (int r = 0; r < 4; ++r) {
                const float p = __expf(sf[j][r] - mrow[r]);
                psum[r] += p;
                pls[wv][4 * g + r][j * 16 + ln] = f2bf(p);
            }
        }
#pragma unroll
        for (int r = 0; r < 4; ++r) {
            float v = psum[r];
            v += __shfl_xor(v, 1);
            v += __shfl_xor(v, 2);
            v += __shfl_xor(v, 4);
            v += __shfl_xor(v, 8);
            lrow[r] = lrow[r] * alpha[r] + v;
        }
#pragma unroll
        for (int nt = 0; nt < 4; ++nt)
#pragma unroll
            for (int r = 0; r < 4; ++r) o[nt][r] *= alpha[r];

        // O += P * VP   (A-frag from per-wave P tile, B-frag from vpT tile)
#pragma unroll
        for (int sk = 0; sk < 2; ++sk) {
            bf16x8 pa = __builtin_bit_cast(bf16x8, *reinterpret_cast<const u16x8*>(&pls[wv][ln][sk * 32 + g * 8]));
#pragma unroll
            for (int nt = 0; nt < 4; ++nt) {
                const int vrow = nt * 16 + ln;
                const int chunk = (sk * 4 + g) ^ (vrow & 7);
                bf16x8 vb = __builtin_bit_cast(bf16x8, *reinterpret_cast<const u16x8*>(vps + vrow * 64 + chunk * 8));
                o[nt] = MFMA16(pa, vb, o[nt]);
            }
        }
    }

    const int b = bh >> 4, h = bh & 15;
#pragma unroll
    for (int r = 0; r < 4; ++r) {
        const float inv = 1.0f / lrow[r];
        const int t = qt * 64 + wv * 16 + 4 * g + r;
        const size_t base = (size_t)(b * 2048 + t) * 1024 + h * 64;
#pragma unroll
        for (int nt = 0; nt < 4; ++nt)
            og[base + nt * 16 + ln] = f2bf(o[nt][r] * inv);
    }
}

// ---------------------------------------------------------------- launch
extern "C" void kernel_launch(void* const* d_in, const int* in_sizes, int n_in,
                              void* d_out, int out_size, void* d_ws, size_t ws_size,
                              hipStream_t stream) {
    const float* x  = (const float*)d_in[0];
    const float* Wq = (const float*)d_in[1];
    const float* Wk = (const float*)d_in[2];
    const float* Wv = (const float*)d_in[3];
    const float* E  = (const float*)d_in[4];
    const float* F  = (const float*)d_in[5];
    const float* Wp = (const float*)d_in[6];
    const float* bp = (const float*)d_in[7];
    float* out = (float*)d_out;

    char* ws = (char*)d_ws;
    unsigned short* xb   = (unsigned short*)(ws);               // 4096x1024 bf16 (8 MB)
    unsigned short* wcat = (unsigned short*)(ws + 8388608);     // 3072x1024 bf16 (6 MB)
    unsigned short* qw   = (unsigned short*)(ws + 14680064);    // [32][2048][64] bf16 (8 MB)
    unsigned short* kpw  = (unsigned short*)(ws + 23068672);    // [32][2048][64] bf16 (8 MB)
    unsigned short* vptw = (unsigned short*)(ws + 31457280);    // [32][64][2048] bf16 (8 MB)
    unsigned short* ow   = (unsigned short*)(ws + 39845888);    // 4096x1024 bf16 (8 MB)
    unsigned short* wpb  = (unsigned short*)(ws + 48234496);    // 1024x1024 bf16 (2 MB)

    // bf16 conversions
    convert_f32_bf16<<<4096, 256, 0, stream>>>(x, xb, 1048576);
    convert_f32_bf16<<<1024, 256, 0, stream>>>(Wq, wcat, 262144);      // rows [0,1024) of wcat
    convert_f32_bf16<<<1024, 256, 0, stream>>>(Wp, wpb, 262144);
    // fold E into Wk, F into Wv -> wcat rows [1024,3072)
    build_wkev<<<8192, 256, 0, stream>>>(Wk, Wv, E, F, wcat);
    // fused q/kp/vp projection GEMM: 4096x3072x1024
    gemm_bt<0><<<dim3(32, 24), 256, 0, stream>>>(xb, wcat, 1024, qw, kpw, vptw, nullptr, nullptr);
    // causal flash attention
    attn_kernel<<<dim3(32, 32), 256, 0, stream>>>(qw, kpw, vptw, ow);
    // output projection + bias: 4096x1024x1024
    gemm_bt<1><<<dim3(32, 8), 256, 0, stream>>>(ow, wpb, 1024, nullptr, nullptr, nullptr, out, bp);
}